// Round 9
// baseline (344.814 us; speedup 1.0000x reference)
//
#include <hip/hip_runtime.h>

// Capsule dynamic routing via MFMA, fused, u_hat never materialized.
//   x: [B=64, In=2048, K=16] fp32;  W: [N=32, In=2048, D=32, K=16] fp32
//   out v: [B=64, N=32, D=32] fp32
// Identities: b_t = u_hat . Vsum (logits linear in agreements); c_1 = 1/32.
// Round-9 structure:
//   kT    : x -> xh/xl bf16 [In][B][K]
//   kS1c  : iter-1 s (uniform c) from fp32 W (bf16x3), fused W->Wb convert
//   kF2 x2: iters 2-3 fully fused: pass1 logits (1 MFMA) -> LDS softmax ->
//           pass2 weighted sum. Block = (8-i slab, 32-b half, all 32 n),
//           512 thr, grid 512 (2 blocks/CU). Pass-2 Wb re-read is L3-resident
//           (67 MB bf16 << 256 MB); b-split doubles the grid vs round-5's
//           1-block/CU failure. c lives only in LDS.
//   kR1h/kR2: wide reduction + squash; vsum stored [N][B][D] (vector loads).
// NOTE (round-3): tiny-grid reduction kernels are latency disasters.
// NOTE (round-5): fusion failed at 1 block/CU + fp32 W; fixed here.
// NOTE (round-8): separate streaming W-convert is net-negative; keep kS1c.

#define INP 2048
#define BB 64
#define KK 16
#define NN 32
#define DD 32
#define ICH 16
#define SCH (INP / ICH)  // 128 chunks (kS1c)
#define FICH 8
#define FNCH (INP / FICH) // 256 chunks (kF2)

typedef __attribute__((ext_vector_type(8))) short short8;
typedef __attribute__((ext_vector_type(16))) float f32x16;

__device__ __forceinline__ short bf_trunc(float f) {
  return (short)(__builtin_bit_cast(unsigned, f) >> 16);
}
__device__ __forceinline__ unsigned short bf_round(float f) {
  unsigned u = __builtin_bit_cast(unsigned, f);
  return (unsigned short)((u + 0x8000u) >> 16);
}
__device__ __forceinline__ float bf2f(unsigned short u) {
  return __builtin_bit_cast(float, (unsigned)u << 16);
}

__device__ __forceinline__ void split8(float4 w0, float4 w1, short8& h, short8& l) {
  float f[8] = {w0.x, w0.y, w0.z, w0.w, w1.x, w1.y, w1.z, w1.w};
#pragma unroll
  for (int j = 0; j < 8; ++j) {
    unsigned u = __builtin_bit_cast(unsigned, f[j]);
    h[j] = (short)(u >> 16);
    float hf = __builtin_bit_cast(float, u & 0xFFFF0000u);
    l[j] = bf_trunc(f[j] - hf);
  }
}
__device__ __forceinline__ short8 round8(float4 w0, float4 w1) {
  float f[8] = {w0.x, w0.y, w0.z, w0.w, w1.x, w1.y, w1.z, w1.w};
  short8 r;
#pragma unroll
  for (int j = 0; j < 8; ++j) r[j] = (short)bf_round(f[j]);
  return r;
}

// ------------------------------------------------------------------ kT
__global__ __launch_bounds__(256) void kT(const float* __restrict__ x,
                                          short* __restrict__ xh,
                                          short* __restrict__ xl) {
  const int t = blockIdx.x * 256 + threadIdx.x; // In*B
  const int i = t >> 6, b = t & 63;
  const float4* xs = (const float4*)(x + ((size_t)b * INP + i) * KK);
  short8* dh = (short8*)(xh + ((size_t)i * BB + b) * KK);
  short8* dl = (short8*)(xl + ((size_t)i * BB + b) * KK);
#pragma unroll
  for (int h = 0; h < 2; ++h) {
    short8 hh, ll;
    split8(xs[h * 2], xs[h * 2 + 1], hh, ll);
    dh[h] = hh;
    dl[h] = ll;
  }
}

// ------------------------------------------------------------------ kS1c
// iter-1 (c=1/32) + W->bf16 convert. wave = (n, i-chunk); bf16 spart.
__global__ __launch_bounds__(256) void kS1c(const float* __restrict__ W,
                                            const short* __restrict__ xh,
                                            const short* __restrict__ xl,
                                            short* __restrict__ Wb,
                                            unsigned short* __restrict__ spart) {
  const int wv = threadIdx.x >> 6;
  const int lane = threadIdx.x & 63;
  const int bl = lane & 31;
  const int hi = lane >> 5;
  const int w = blockIdx.x * 4 + wv;
  const int n = w >> 7;          // / SCH
  const int ch = w & (SCH - 1);

  f32x16 s0 = {};
  f32x16 s1 = {};

  const size_t fragoff = (((size_t)n * INP + (size_t)ch * ICH) * DD + bl) * KK + hi * 8;
  const float* Wp = W + fragoff;
  short* Wbp = Wb + fragoff;
  const short* xhp = xh + (size_t)ch * ICH * BB * KK + hi * 8;
  const short* xlp = xl + (size_t)ch * ICH * BB * KK + hi * 8;

#pragma unroll 2
  for (int ii = 0; ii < ICH; ++ii) {
    float4 w0 = *(const float4*)(Wp + (size_t)ii * (DD * KK));
    float4 w1 = *(const float4*)(Wp + (size_t)ii * (DD * KK) + 4);
    short8 whi, wlo;
    split8(w0, w1, whi, wlo);
    *(short8*)(Wbp + (size_t)ii * (DD * KK)) = round8(w0, w1);
    const short8 x0h = *(const short8*)(xhp + ii * (BB * KK) + bl * KK);
    const short8 x0l = *(const short8*)(xlp + ii * (BB * KK) + bl * KK);
    const short8 x1h = *(const short8*)(xhp + ii * (BB * KK) + (bl + 32) * KK);
    const short8 x1l = *(const short8*)(xlp + ii * (BB * KK) + (bl + 32) * KK);
    s0 = __builtin_amdgcn_mfma_f32_32x32x16_bf16(whi, x0h, s0, 0, 0, 0);
    s0 = __builtin_amdgcn_mfma_f32_32x32x16_bf16(whi, x0l, s0, 0, 0, 0);
    s0 = __builtin_amdgcn_mfma_f32_32x32x16_bf16(wlo, x0h, s0, 0, 0, 0);
    s1 = __builtin_amdgcn_mfma_f32_32x32x16_bf16(whi, x1h, s1, 0, 0, 0);
    s1 = __builtin_amdgcn_mfma_f32_32x32x16_bf16(whi, x1l, s1, 0, 0, 0);
    s1 = __builtin_amdgcn_mfma_f32_32x32x16_bf16(wlo, x1h, s1, 0, 0, 0);
  }

  const size_t off = ((size_t)ch * NN + n) * (DD * BB);
#pragma unroll
  for (int r = 0; r < 16; ++r) {
    const int d = (r & 3) + 8 * (r >> 2) + 4 * hi;
    spart[off + d * BB + bl] = bf_round(0.03125f * s0[r]);
    spart[off + d * BB + bl + 32] = bf_round(0.03125f * s1[r]);
  }
}

// ------------------------------------------------------------------ kF2
// fused iteration: block = (i-slab of 8, b-half of 32, all 32 n); 8 waves,
// each wave 4 n. pass1: logits (1 MFMA) -> LDS; softmax; pass2: s accumulate.
// vsumT layout [N][B][D] -> 4x float4 per (n, lane).
__global__ __launch_bounds__(512, 4) void kF2(const short* __restrict__ Wb,
                                              const short* __restrict__ xh,
                                              const short* __restrict__ xl,
                                              const float* __restrict__ vsumT,
                                              unsigned short* __restrict__ spart) {
  __shared__ unsigned short sm[FICH][32][NN + 2]; // 17.4 KB, 17-bank stride
  const int w = threadIdx.x >> 6;
  const int lane = threadIdx.x & 63;
  const int bl = lane & 31;
  const int hi = lane >> 5;
  const int bi = blockIdx.x;
  const int ch = bi >> 1;      // i-chunk (twins adjacent for L2/L3 sharing)
  const int bh = bi & 1;       // b-half
  const size_t i0 = (size_t)ch * FICH;

  const short* xbase_h = xh + (i0 * BB + (size_t)bh * 32 + bl) * KK + hi * 8;
  const short* xbase_l = xl + (i0 * BB + (size_t)bh * 32 + bl) * KK + hi * 8;

  // ---- pass 1: raw logits -> sm
  for (int nr = 0; nr < 4; ++nr) {
    const int n = w * 4 + nr;
    float vr[16];
    const float* vp = vsumT + ((size_t)n * BB + bh * 32 + bl) * DD + hi * 4;
#pragma unroll
    for (int g = 0; g < 4; ++g) {
      float4 v4 = *(const float4*)(vp + g * 8);
      vr[g * 4 + 0] = v4.x;
      vr[g * 4 + 1] = v4.y;
      vr[g * 4 + 2] = v4.z;
      vr[g * 4 + 3] = v4.w;
    }
    const short* Wp = Wb + (((size_t)n * INP + i0) * DD + bl) * KK + hi * 8;
#pragma unroll 2
    for (int ii = 0; ii < FICH; ++ii) {
      const short8 wf = *(const short8*)(Wp + (size_t)ii * (DD * KK));
      const short8 xf = *(const short8*)(xbase_h + (size_t)ii * (BB * KK));
      f32x16 u = {};
      u = __builtin_amdgcn_mfma_f32_32x32x16_bf16(wf, xf, u, 0, 0, 0);
      float p = 0.f;
#pragma unroll
      for (int r = 0; r < 16; ++r) p += u[r] * vr[r];
      p += __shfl_xor(p, 32, 64);
      if (hi == 0) sm[ii][bl][n] = bf_round(p);
    }
  }
  __syncthreads();

  // ---- softmax over n per (ii, b); threads 0..255
  if (threadIdx.x < 256) {
    const int ii = threadIdx.x >> 5;
    const int b = threadIdx.x & 31;
    unsigned* row = (unsigned*)&sm[ii][b][0];
    float a[NN];
    float m = -1e30f;
#pragma unroll
    for (int j = 0; j < 16; ++j) {
      const unsigned u = row[j];
      a[2 * j] = bf2f((unsigned short)(u & 0xFFFFu));
      a[2 * j + 1] = bf2f((unsigned short)(u >> 16));
      m = fmaxf(m, fmaxf(a[2 * j], a[2 * j + 1]));
    }
    float s = 0.f;
#pragma unroll
    for (int n = 0; n < NN; ++n) {
      a[n] = __expf(a[n] - m);
      s += a[n];
    }
    const float inv = 1.f / s;
#pragma unroll
    for (int j = 0; j < 16; ++j) {
      const unsigned lo = bf_round(a[2 * j] * inv);
      const unsigned hs = bf_round(a[2 * j + 1] * inv);
      row[j] = lo | (hs << 16);
    }
  }
  __syncthreads();

  // ---- pass 2: weighted sum (Wb slab from L2/L3)
  for (int nr = 0; nr < 4; ++nr) {
    const int n = w * 4 + nr;
    f32x16 s = {};
    const short* Wp = Wb + (((size_t)n * INP + i0) * DD + bl) * KK + hi * 8;
#pragma unroll 2
    for (int ii = 0; ii < FICH; ++ii) {
      const short8 wf = *(const short8*)(Wp + (size_t)ii * (DD * KK));
      const short8 xfh = *(const short8*)(xbase_h + (size_t)ii * (BB * KK));
      const short8 xfl = *(const short8*)(xbase_l + (size_t)ii * (BB * KK));
      f32x16 u = {};
      u = __builtin_amdgcn_mfma_f32_32x32x16_bf16(wf, xfh, u, 0, 0, 0);
      u = __builtin_amdgcn_mfma_f32_32x32x16_bf16(wf, xfl, u, 0, 0, 0);
      const float c = bf2f(sm[ii][bl][n]);
#pragma unroll
      for (int r = 0; r < 16; ++r) s[r] += c * u[r];
    }
    const size_t off = ((size_t)ch * NN + n) * (DD * BB) + bh * 32;
#pragma unroll
    for (int r = 0; r < 16; ++r) {
      const int d = (r & 3) + 8 * (r >> 2) + 4 * hi;
      spart[off + d * BB + bl] = bf_round(s[r]);
    }
  }
}

// ------------------------------------------------------------------ kR1h
// bf16 spart [nch][N][D][B] -> st fp32 [N][D][B]; uint loads.
__global__ void kR1h(const unsigned* __restrict__ spart, float2* __restrict__ st,
                     int nch) {
  const int t = blockIdx.x * 128 + threadIdx.x; // 32768 uint cells
  float s0 = 0.f, s1 = 0.f;
  for (int ch = 0; ch < nch; ++ch) {
    const unsigned u = spart[(size_t)ch * (NN * DD * BB / 2) + t];
    s0 += bf2f((unsigned short)(u & 0xFFFFu));
    s1 += bf2f((unsigned short)(u >> 16));
  }
  st[t] = make_float2(s0, s1);
}

// ------------------------------------------------------------------ kR2
// squash per (b,n); vsumT [N][B][D] = (first ? v : vsumT + v); out on last.
__global__ void kR2(const float* __restrict__ st, float* __restrict__ vsumT,
                    float* __restrict__ out, int first, int last) {
  const int t = blockIdx.x * 64 + threadIdx.x; // B*N = 2048
  const int b = t & 63;
  const int n = t >> 6;
  float sd[DD];
  float s2 = 0.f;
#pragma unroll
  for (int d = 0; d < DD; ++d) {
    sd[d] = st[(n * DD + d) * BB + b];
    s2 += sd[d] * sd[d];
  }
  const float scale = s2 / (1.f + s2) / sqrtf(s2 + 1e-7f);
  float* vp = vsumT + ((size_t)n * BB + b) * DD;
#pragma unroll
  for (int d = 0; d < DD; ++d) {
    const float v = scale * sd[d];
    vp[d] = first ? v : (vp[d] + v);
    if (last) out[((size_t)b * NN + n) * DD + d] = v;
  }
}

extern "C" void kernel_launch(void* const* d_in, const int* in_sizes, int n_in,
                              void* d_out, int out_size, void* d_ws,
                              size_t ws_size, hipStream_t stream) {
  const float* x = (const float*)d_in[0]; // [64,2048,16]
  const float* W = (const float*)d_in[1]; // [32,2048,32,16]
  float* out = (float*)d_out;             // [64,32,32]

  short* xh = (short*)d_ws;                            // 4.2 MB
  short* xl = xh + (size_t)INP * BB * KK;              // 4.2 MB
  short* Wbuf = xl + (size_t)INP * BB * KK;            // bf16 W, 67 MB
  unsigned short* sparth = (unsigned short*)(Wbuf + (size_t)NN * INP * DD * KK); // 33.5 MB
  float* st = (float*)(sparth + (size_t)FNCH * NN * DD * BB); // 256 KB
  float* vsumT = st + (size_t)NN * DD * BB;                    // 256 KB [N][B][D]

  const int gS = (NN * SCH) / 4;   // 1024 blocks
  const int gT = (INP * BB) / 256; // 512
  const int gF = FNCH * 2;         // 512 blocks (i-chunk x b-half twins)
  const int gR1 = (NN * DD * BB / 2) / 128; // 256
  const int gR2 = (BB * NN) / 64;  // 32

  kT<<<gT, 256, 0, stream>>>(x, xh, xl);

  // iteration 1: c uniform; converts W -> Wb; vsumT = v (first)
  kS1c<<<gS, 256, 0, stream>>>(W, xh, xl, Wbuf, sparth);
  kR1h<<<gR1, 128, 0, stream>>>((const unsigned*)sparth, (float2*)st, SCH);
  kR2<<<gR2, 64, 0, stream>>>(st, vsumT, out, 1, 0);
  // iterations 2..3: fully fused
  for (int it = 1; it < 3; ++it) {
    kF2<<<gF, 512, 0, stream>>>(Wbuf, xh, xl, vsumT, sparth);
    kR1h<<<gR1, 128, 0, stream>>>((const unsigned*)sparth, (float2*)st, FNCH);
    kR2<<<gR2, 64, 0, stream>>>(st, vsumT, out, 0, it == 2);
  }
}

// Round 10
// 176.626 us; speedup vs baseline: 1.9522x; 1.9522x over previous
//
#include <hip/hip_runtime.h>

// Capsule dynamic routing via MFMA, fused, u_hat never materialized.
//   x: [B=64, In=2048, K=16] fp32;  W: [N=32, In=2048, D=32, K=16] fp32
//   out v: [B=64, N=32, D=32] fp32
// Identities: b_t = u_hat . Vsum (logits linear in agreements); c_1 = 1/32.
// Per (n,i): u[d,b] = W[n,i] (32x16) @ x^T (16x64) via 2 b-tiles of
// mfma_f32_32x32x16_bf16.
// Structure (round-7 skeleton, best measured = 186 us):
//   kT   : x -> xh/xl bf16 [In][B][K]
//   kS1c : iter-1 s (uniform c=1/32) from fp32 W (bf16x3), fused W->Wb convert
//   kA   : logits (single MFMA, Wb*xh), chunk=8 -> 32 waves/CU
//   kSM  : softmax over n (in-place, bf16 ct)
//   kS   : weighted sum (Wb, x hi+lo), chunk=16, bf16 spart
//   kR1h/kR2 : wide reduction + squash; vsum [N][D][B] fp32
// NOTE (round-3): tiny-grid reduction kernels are latency disasters.
// NOTE (rounds 5/8/9): ALL fusion attempts (2-pass LDS-softmax blocks,
// separate W-convert) lost 30-160 us. The streaming skeleton wins; the
// kernels are latency-bound, so wave count (TLP) is the lever that works.

#define INP 2048
#define BB 64
#define KK 16
#define NN 32
#define DD 32
#define ICH 16
#define NCHUNK (INP / ICH) // 128 (kS1c, kS, spart)
#define ACH 8
#define ANCH (INP / ACH)   // 256 (kA)

typedef __attribute__((ext_vector_type(8))) short short8;
typedef __attribute__((ext_vector_type(16))) float f32x16;

__device__ __forceinline__ short bf_trunc(float f) {
  return (short)(__builtin_bit_cast(unsigned, f) >> 16);
}
__device__ __forceinline__ unsigned short bf_round(float f) {
  unsigned u = __builtin_bit_cast(unsigned, f);
  return (unsigned short)((u + 0x8000u) >> 16);
}
__device__ __forceinline__ float bf2f(unsigned short u) {
  return __builtin_bit_cast(float, (unsigned)u << 16);
}

__device__ __forceinline__ void split8(float4 w0, float4 w1, short8& h, short8& l) {
  float f[8] = {w0.x, w0.y, w0.z, w0.w, w1.x, w1.y, w1.z, w1.w};
#pragma unroll
  for (int j = 0; j < 8; ++j) {
    unsigned u = __builtin_bit_cast(unsigned, f[j]);
    h[j] = (short)(u >> 16);
    float hf = __builtin_bit_cast(float, u & 0xFFFF0000u);
    l[j] = bf_trunc(f[j] - hf);
  }
}

// round-to-nearest bf16 of 8 fp32 (for the stored Wb)
__device__ __forceinline__ short8 round8(float4 w0, float4 w1) {
  float f[8] = {w0.x, w0.y, w0.z, w0.w, w1.x, w1.y, w1.z, w1.w};
  short8 r;
#pragma unroll
  for (int j = 0; j < 8; ++j) r[j] = (short)bf_round(f[j]);
  return r;
}

// ------------------------------------------------------------------ kT
// transpose x [B][In][K] fp32 -> xt_hi/xt_lo [In][B][K] bf16
__global__ __launch_bounds__(256) void kT(const float* __restrict__ x,
                                          short* __restrict__ xh,
                                          short* __restrict__ xl) {
  const int t = blockIdx.x * 256 + threadIdx.x; // In*B = 131072
  const int i = t >> 6, b = t & 63;
  const float4* xs = (const float4*)(x + ((size_t)b * INP + i) * KK);
  short8* dh = (short8*)(xh + ((size_t)i * BB + b) * KK);
  short8* dl = (short8*)(xl + ((size_t)i * BB + b) * KK);
#pragma unroll
  for (int h = 0; h < 2; ++h) {
    short8 hh, ll;
    split8(xs[h * 2], xs[h * 2 + 1], hh, ll);
    dh[h] = hh;
    dl[h] = ll;
  }
}

// ------------------------------------------------------------------ kS1c
// iteration 1 (c uniform = 1/32) + W->bf16 conversion. wave = (n, i-chunk).
// bf16x3 MFMA from fp32 W; writes Wb and bf16 spart.
__global__ __launch_bounds__(256) void kS1c(const float* __restrict__ W,
                                            const short* __restrict__ xh,
                                            const short* __restrict__ xl,
                                            short* __restrict__ Wb,
                                            unsigned short* __restrict__ spart) {
  const int wv = threadIdx.x >> 6;
  const int lane = threadIdx.x & 63;
  const int bl = lane & 31;
  const int hi = lane >> 5;
  const int w = blockIdx.x * 4 + wv;
  const int n = w >> 7;          // / NCHUNK
  const int ch = w & (NCHUNK - 1);

  f32x16 s0 = {};
  f32x16 s1 = {};

  const size_t fragoff = (((size_t)n * INP + (size_t)ch * ICH) * DD + bl) * KK + hi * 8;
  const float* Wp = W + fragoff;
  short* Wbp = Wb + fragoff;
  const short* xhp = xh + (size_t)ch * ICH * BB * KK + hi * 8;
  const short* xlp = xl + (size_t)ch * ICH * BB * KK + hi * 8;

#pragma unroll 2
  for (int ii = 0; ii < ICH; ++ii) {
    float4 w0 = *(const float4*)(Wp + (size_t)ii * (DD * KK));
    float4 w1 = *(const float4*)(Wp + (size_t)ii * (DD * KK) + 4);
    short8 whi, wlo;
    split8(w0, w1, whi, wlo);
    *(short8*)(Wbp + (size_t)ii * (DD * KK)) = round8(w0, w1); // store Wb
    const short8 x0h = *(const short8*)(xhp + ii * (BB * KK) + bl * KK);
    const short8 x0l = *(const short8*)(xlp + ii * (BB * KK) + bl * KK);
    const short8 x1h = *(const short8*)(xhp + ii * (BB * KK) + (bl + 32) * KK);
    const short8 x1l = *(const short8*)(xlp + ii * (BB * KK) + (bl + 32) * KK);
    s0 = __builtin_amdgcn_mfma_f32_32x32x16_bf16(whi, x0h, s0, 0, 0, 0);
    s0 = __builtin_amdgcn_mfma_f32_32x32x16_bf16(whi, x0l, s0, 0, 0, 0);
    s0 = __builtin_amdgcn_mfma_f32_32x32x16_bf16(wlo, x0h, s0, 0, 0, 0);
    s1 = __builtin_amdgcn_mfma_f32_32x32x16_bf16(whi, x1h, s1, 0, 0, 0);
    s1 = __builtin_amdgcn_mfma_f32_32x32x16_bf16(whi, x1l, s1, 0, 0, 0);
    s1 = __builtin_amdgcn_mfma_f32_32x32x16_bf16(wlo, x1h, s1, 0, 0, 0);
  }

  const size_t off = ((size_t)ch * NN + n) * (DD * BB);
#pragma unroll
  for (int r = 0; r < 16; ++r) {
    const int d = (r & 3) + 8 * (r >> 2) + 4 * hi;
    spart[off + d * BB + bl] = bf_round(0.03125f * s0[r]);
    spart[off + d * BB + bl + 32] = bf_round(0.03125f * s1[r]);
  }
}

// ------------------------------------------------------------------ kA
// wave = (n, i-chunk of 8). a[b,n,i] = sum_d u[d,b]*vsum[b,n,d] -> ct bf16.
// single-MFMA u (x hi only): logit error is softmax-damped + i-averaged.
// chunk=8 -> 2048 blocks = 32 waves/CU (pure TLP, no extra HBM traffic).
__global__ __launch_bounds__(256) void kA(const short* __restrict__ Wb,
                                          const short* __restrict__ xh,
                                          const float* __restrict__ vsum,
                                          unsigned short* __restrict__ ct) {
  const int wv = threadIdx.x >> 6;
  const int lane = threadIdx.x & 63;
  const int bl = lane & 31;
  const int hi = lane >> 5;
  const int w = blockIdx.x * 4 + wv;
  const int n = w >> 8;           // / ANCH
  const int ch = w & (ANCH - 1);

  float vr0[16], vr1[16];
#pragma unroll
  for (int r = 0; r < 16; ++r) {
    const int d = (r & 3) + 8 * (r >> 2) + 4 * hi;
    vr0[r] = vsum[((size_t)n * DD + d) * BB + bl];
    vr1[r] = vsum[((size_t)n * DD + d) * BB + bl + 32];
  }

  const short* Wp = Wb + (((size_t)n * INP + (size_t)ch * ACH) * DD + bl) * KK + hi * 8;
  const short* xhp = xh + (size_t)ch * ACH * BB * KK + hi * 8;

#pragma unroll 2
  for (int ii = 0; ii < ACH; ++ii) {
    const short8 whi = *(const short8*)(Wp + (size_t)ii * (DD * KK));
    const short8 x0h = *(const short8*)(xhp + ii * (BB * KK) + bl * KK);
    const short8 x1h = *(const short8*)(xhp + ii * (BB * KK) + (bl + 32) * KK);

    f32x16 u0 = {};
    u0 = __builtin_amdgcn_mfma_f32_32x32x16_bf16(whi, x0h, u0, 0, 0, 0);
    f32x16 u1 = {};
    u1 = __builtin_amdgcn_mfma_f32_32x32x16_bf16(whi, x1h, u1, 0, 0, 0);

    float p0 = 0.f, p1 = 0.f;
#pragma unroll
    for (int r = 0; r < 16; ++r) {
      p0 += u0[r] * vr0[r];
      p1 += u1[r] * vr1[r];
    }
    p0 += __shfl_xor(p0, 32, 64);
    p1 += __shfl_xor(p1, 32, 64);
    const int i = ch * ACH + ii;
    ct[((size_t)i * NN + n) * BB + lane] = bf_round((lane < 32) ? p0 : p1);
  }
}

// ------------------------------------------------------------------ kSM
// in-place softmax over n for each (i, b); wave per i, lane = b. bf16 ct.
__global__ __launch_bounds__(256) void kSM(unsigned short* __restrict__ ct) {
  const int wv = threadIdx.x >> 6;
  const int lane = threadIdx.x & 63;
  const int i = blockIdx.x * 4 + wv;
  unsigned short* p = ct + (size_t)i * NN * BB + lane;
  float a[NN];
  float m = -1e30f;
#pragma unroll
  for (int n = 0; n < NN; ++n) {
    a[n] = bf2f(p[n * BB]);
    m = fmaxf(m, a[n]);
  }
  float s = 0.f;
#pragma unroll
  for (int n = 0; n < NN; ++n) {
    a[n] = __expf(a[n] - m);
    s += a[n];
  }
  const float inv = 1.f / s;
#pragma unroll
  for (int n = 0; n < NN; ++n) p[n * BB] = bf_round(a[n] * inv);
}

// ------------------------------------------------------------------ kS
// iterations 2-3: wave = (n, i-chunk of 16). s_acc += c * u; bf16 spart.
__global__ __launch_bounds__(256) void kS(const short* __restrict__ Wb,
                                          const short* __restrict__ xh,
                                          const short* __restrict__ xl,
                                          const unsigned short* __restrict__ ct,
                                          unsigned short* __restrict__ spart) {
  const int wv = threadIdx.x >> 6;
  const int lane = threadIdx.x & 63;
  const int bl = lane & 31;
  const int hi = lane >> 5;
  const int w = blockIdx.x * 4 + wv;
  const int n = w >> 7;
  const int ch = w & (NCHUNK - 1);

  f32x16 s0 = {};
  f32x16 s1 = {};

  const short* Wp = Wb + (((size_t)n * INP + (size_t)ch * ICH) * DD + bl) * KK + hi * 8;
  const short* xhp = xh + (size_t)ch * ICH * BB * KK + hi * 8;
  const short* xlp = xl + (size_t)ch * ICH * BB * KK + hi * 8;

#pragma unroll 2
  for (int ii = 0; ii < ICH; ++ii) {
    const short8 whi = *(const short8*)(Wp + (size_t)ii * (DD * KK));
    const short8 x0h = *(const short8*)(xhp + ii * (BB * KK) + bl * KK);
    const short8 x0l = *(const short8*)(xlp + ii * (BB * KK) + bl * KK);
    const short8 x1h = *(const short8*)(xhp + ii * (BB * KK) + (bl + 32) * KK);
    const short8 x1l = *(const short8*)(xlp + ii * (BB * KK) + (bl + 32) * KK);

    f32x16 u0 = {};
    u0 = __builtin_amdgcn_mfma_f32_32x32x16_bf16(whi, x0h, u0, 0, 0, 0);
    u0 = __builtin_amdgcn_mfma_f32_32x32x16_bf16(whi, x0l, u0, 0, 0, 0);
    f32x16 u1 = {};
    u1 = __builtin_amdgcn_mfma_f32_32x32x16_bf16(whi, x1h, u1, 0, 0, 0);
    u1 = __builtin_amdgcn_mfma_f32_32x32x16_bf16(whi, x1l, u1, 0, 0, 0);

    const int i = ch * ICH + ii;
    const float c0 = bf2f(ct[((size_t)i * NN + n) * BB + bl]);
    const float c1 = bf2f(ct[((size_t)i * NN + n) * BB + bl + 32]);
#pragma unroll
    for (int r = 0; r < 16; ++r) {
      s0[r] += c0 * u0[r];
      s1[r] += c1 * u1[r];
    }
  }

  const size_t off = ((size_t)ch * NN + n) * (DD * BB);
#pragma unroll
  for (int r = 0; r < 16; ++r) {
    const int d = (r & 3) + 8 * (r >> 2) + 4 * hi;
    spart[off + d * BB + bl] = bf_round(s0[r]);
    spart[off + d * BB + bl + 32] = bf_round(s1[r]);
  }
}

// ------------------------------------------------------------------ kR1h
// bf16 spart [128][N][D][B] -> st fp32; uint loads (2 elems/thread).
__global__ void kR1h(const unsigned* __restrict__ spart, float2* __restrict__ st) {
  const int t = blockIdx.x * 128 + threadIdx.x; // 32768 uint cells
  float s0 = 0.f, s1 = 0.f;
  for (int ch = 0; ch < NCHUNK; ++ch) {
    const unsigned u = spart[(size_t)ch * (NN * DD * BB / 2) + t];
    s0 += bf2f((unsigned short)(u & 0xFFFFu));
    s1 += bf2f((unsigned short)(u >> 16));
  }
  st[t] = make_float2(s0, s1);
}

// ------------------------------------------------------------------ kR2
// squash per (b,n); vsum = (first ? v : vsum + v); write out on last.
__global__ void kR2(const float* __restrict__ st, float* __restrict__ vsum,
                    float* __restrict__ out, int first, int last) {
  const int t = blockIdx.x * 64 + threadIdx.x; // B*N = 2048
  const int b = t & 63;
  const int n = t >> 6;
  float sd[DD];
  float s2 = 0.f;
#pragma unroll
  for (int d = 0; d < DD; ++d) {
    sd[d] = st[(n * DD + d) * BB + b];
    s2 += sd[d] * sd[d];
  }
  const float scale = s2 / (1.f + s2) / sqrtf(s2 + 1e-7f);
#pragma unroll
  for (int d = 0; d < DD; ++d) {
    const float v = scale * sd[d];
    const size_t idx = (size_t)(n * DD + d) * BB + b;
    vsum[idx] = first ? v : (vsum[idx] + v);
    if (last) out[((size_t)b * NN + n) * DD + d] = v;
  }
}

extern "C" void kernel_launch(void* const* d_in, const int* in_sizes, int n_in,
                              void* d_out, int out_size, void* d_ws,
                              size_t ws_size, hipStream_t stream) {
  const float* x = (const float*)d_in[0]; // [64,2048,16]
  const float* W = (const float*)d_in[1]; // [32,2048,32,16]
  float* out = (float*)d_out;             // [64,32,32]

  short* xh = (short*)d_ws;                            // [In][B][K] bf16 4.2 MB
  short* xl = xh + (size_t)INP * BB * KK;              // 4.2 MB
  short* Wbuf = xl + (size_t)INP * BB * KK;            // [N][In][D][K] bf16 67 MB
  unsigned short* ct = (unsigned short*)(Wbuf + (size_t)NN * INP * DD * KK); // 8.4 MB
  unsigned short* sparth = ct + (size_t)INP * NN * BB; // [128][N][D][B] bf16 16.8 MB
  float* st = (float*)(sparth + (size_t)NCHUNK * NN * DD * BB); // 256 KB
  float* vsum = st + (size_t)NN * DD * BB;                       // 256 KB

  const int gW = (NN * NCHUNK) / 4;          // 1024 blocks, 4 waves each
  const int gA = (NN * ANCH) / 4;            // 2048 blocks
  const int gT = (INP * BB) / 256;           // 512
  const int gSM = INP / 4;                   // 512
  const int gR1h = (NN * DD * BB / 2) / 128; // 256
  const int gR2 = (BB * NN) / 64;            // 32

  kT<<<gT, 256, 0, stream>>>(x, xh, xl);

  // iteration 1: c uniform; also converts W -> Wb; vsum = v (first)
  kS1c<<<gW, 256, 0, stream>>>(W, xh, xl, Wbuf, sparth);
  kR1h<<<gR1h, 128, 0, stream>>>((const unsigned*)sparth, (float2*)st);
  kR2<<<gR2, 64, 0, stream>>>(st, vsum, out, 1, 0);
  // iterations 2..3 on bf16 W
  for (int it = 1; it < 3; ++it) {
    kA<<<gA, 256, 0, stream>>>(Wbuf, xh, vsum, ct);
    kSM<<<gSM, 256, 0, stream>>>(ct);
    kS<<<gW, 256, 0, stream>>>(Wbuf, xh, xl, ct, sparth);
    kR1h<<<gR1h, 128, 0, stream>>>((const unsigned*)sparth, (float2*)st);
    kR2<<<gR2, 64, 0, stream>>>(st, vsum, out, 0, it == 2);
  }
}